// Round 1
// baseline (934.527 us; speedup 1.0000x reference)
//
#include <hip/hip_runtime.h>

// CFConv fused kernel for MI355X (gfx950).
// B=4, N=4096, K=30 (edges), C=64, E=300.
// out[b,n,c] = sum_k x[b, E_idx[b,n,k], c] * gelu(gelu(ef[b,n,k,:]@W1+b1)@W2+b2)[c]
//
// Strategy: bf16 MFMA (16x16x32) for both GEMMs; edge_features streamed
// global->registers directly in A-fragment layout (no LDS staging, no
// barriers in main loop); W1/W2 staged once per block in swizzled LDS;
// h round-trips through wave-private swizzled LDS tile; final K-reduction
// from accumulator C-layout via shfl_xor butterflies.

typedef __bf16 bf16x8 __attribute__((ext_vector_type(8)));
typedef float f32x4 __attribute__((ext_vector_type(4)));

#define B_    4
#define N_    4096
#define K_    30      // edges per node
#define C_    64
#define E_    300
#define EPAD  320     // K-dim of GEMM1 padded to 5 chunks of 64

__device__ __forceinline__ float gelu_exact(float v) {
    // torch exact GELU: 0.5*x*(1+erf(x/sqrt(2)))
    return 0.5f * v * (1.0f + erff(v * 0.70710678118654752440f));
}

__global__ __launch_bounds__(256, 2) void cfconv_kernel(
    const float* __restrict__ x,      // [B,N,C]
    const float* __restrict__ ef,     // [B,N,K,E]
    const int*   __restrict__ eidx,   // [B,N,K]
    const float* __restrict__ W1,     // [E,C]
    const float* __restrict__ b1,     // [C]
    const float* __restrict__ W2,     // [C,C]
    const float* __restrict__ b2,     // [C]
    float*       __restrict__ out,    // [B,N,C]
    int nquads)                       // B*N/4
{
    // LDS: exactly 64 KB total -> 2 blocks/CU (128 KB of 160 KB).
    __shared__ __align__(16) __bf16 Bt[64 * EPAD];   // W1^T swizzled: 40 KB
    __shared__ __align__(16) __bf16 W2t[64 * 64];    // W2^T swizzled:  8 KB
    __shared__ __align__(16) __bf16 Hb[128 * 64];    // h tiles:       16 KB

    const int tid = threadIdx.x;
    const int w   = tid >> 6;   // wave 0..3 -> group within quad
    const int l   = tid & 63;   // lane
    const int m16 = l & 15;     // row/col within 16
    const int q   = l >> 4;     // lane quad 0..3

    // ---- Stage W1 -> Bt (transposed to [n][k], bf16, XOR-swizzled blocks) ----
    for (int e = tid; e < 64 * EPAD; e += 256) {
        int k = e >> 6, n = e & 63;
        float v = (k < E_) ? W1[k * 64 + n] : 0.0f;
        int lb = k >> 3;
        int pb = (lb & ~7) | ((lb & 7) ^ (n & 7));
        Bt[n * EPAD + pb * 8 + (k & 7)] = (__bf16)v;
    }
    // ---- Stage W2 -> W2t (transposed [n][k], swizzled) ----
    for (int e = tid; e < 64 * 64; e += 256) {
        int k = e >> 6, n = e & 63;
        int pb = (k >> 3) ^ (n & 7);
        W2t[n * 64 + pb * 8 + (k & 7)] = (__bf16)W2[k * 64 + n];
    }
    // Per-lane bias values for the 4 column tiles
    float b1v[4], b2v[4];
#pragma unroll
    for (int ct = 0; ct < 4; ++ct) {
        b1v[ct] = b1[ct * 16 + m16];
        b2v[ct] = b2[ct * 16 + m16];
    }
    __syncthreads();  // only barrier needed; weights are read-only afterwards

    __bf16* hw = &Hb[w * 32 * 64];  // wave-private h tile [32 rows][64 cols]

    for (int quad = blockIdx.x; quad < nquads; quad += gridDim.x) {
        const int gq = quad * 4 + w;                   // group id = b*N + n
        const float* efg = ef + (size_t)gq * (K_ * E_);

        // ================= GEMM1: h_pre = ef @ W1 =================
        f32x4 acc1[2][4];
#pragma unroll
        for (int rt = 0; rt < 2; ++rt)
#pragma unroll
            for (int ct = 0; ct < 4; ++ct)
                acc1[rt][ct] = (f32x4){0.f, 0.f, 0.f, 0.f};

#pragma unroll
        for (int kc = 0; kc < 5; ++kc) {
            // A-fragments straight from global (lane m=l&15 row, k contiguous 8)
            bf16x8 af[2][2];
#pragma unroll
            for (int rt = 0; rt < 2; ++rt) {
                int r = rt * 16 + m16;
#pragma unroll
                for (int kh = 0; kh < 2; ++kh) {
                    int k0 = kc * 64 + kh * 32 + q * 8;
                    f32x4 v0 = (f32x4){0.f, 0.f, 0.f, 0.f};
                    f32x4 v1 = (f32x4){0.f, 0.f, 0.f, 0.f};
                    if (r < K_ && k0 < E_) {
                        const float* p = efg + r * E_ + k0;
                        v0 = *(const f32x4*)p;
                        if (k0 + 4 < E_) v1 = *(const f32x4*)(p + 4);
                    }
                    bf16x8 a;
                    a[0] = (__bf16)v0[0]; a[1] = (__bf16)v0[1];
                    a[2] = (__bf16)v0[2]; a[3] = (__bf16)v0[3];
                    a[4] = (__bf16)v1[0]; a[5] = (__bf16)v1[1];
                    a[6] = (__bf16)v1[2]; a[7] = (__bf16)v1[3];
                    af[rt][kh] = a;
                }
            }
            // B-fragments from swizzled LDS (lane n=l&15 col, k contiguous 8)
            bf16x8 bfr[4][2];
#pragma unroll
            for (int ct = 0; ct < 4; ++ct) {
                int n = ct * 16 + m16;
#pragma unroll
                for (int kh = 0; kh < 2; ++kh) {
                    int lb = kc * 8 + kh * 4 + q;
                    int pb = (lb & ~7) | ((lb & 7) ^ (n & 7));
                    bfr[ct][kh] = *(const bf16x8*)&Bt[n * EPAD + pb * 8];
                }
            }
#pragma unroll
            for (int kh = 0; kh < 2; ++kh)
#pragma unroll
                for (int rt = 0; rt < 2; ++rt)
#pragma unroll
                    for (int ct = 0; ct < 4; ++ct)
                        acc1[rt][ct] = __builtin_amdgcn_mfma_f32_16x16x32_bf16(
                            af[rt][kh], bfr[ct][kh], acc1[rt][ct], 0, 0, 0);
        }

        // ====== h = gelu(h_pre + b1) -> wave-private swizzled LDS ======
        // C-layout: row = rt*16 + q*4 + reg, col = ct*16 + m16
#pragma unroll
        for (int rt = 0; rt < 2; ++rt)
#pragma unroll
            for (int ct = 0; ct < 4; ++ct)
#pragma unroll
                for (int reg = 0; reg < 4; ++reg) {
                    int r = rt * 16 + q * 4 + reg;
                    int c = ct * 16 + m16;
                    float hv = gelu_exact(acc1[rt][ct][reg] + b1v[ct]);
                    hw[r * 64 + (((c >> 3) ^ (r & 7)) << 3) + (c & 7)] = (__bf16)hv;
                }

        // ================= GEMM2: w_pre = h @ W2 =================
        f32x4 acc2[2][4];
#pragma unroll
        for (int rt = 0; rt < 2; ++rt)
#pragma unroll
            for (int ct = 0; ct < 4; ++ct)
                acc2[rt][ct] = (f32x4){0.f, 0.f, 0.f, 0.f};

        bf16x8 ah[2][2];
#pragma unroll
        for (int rt = 0; rt < 2; ++rt) {
            int m = rt * 16 + m16;
#pragma unroll
            for (int kh = 0; kh < 2; ++kh) {
                int lb = kh * 4 + q;
                ah[rt][kh] = *(const bf16x8*)&hw[m * 64 + ((lb ^ (m & 7)) << 3)];
            }
        }
        bf16x8 bw[4][2];
#pragma unroll
        for (int ct = 0; ct < 4; ++ct) {
            int n = ct * 16 + m16;
#pragma unroll
            for (int kh = 0; kh < 2; ++kh) {
                int lb = kh * 4 + q;
                bw[ct][kh] = *(const bf16x8*)&W2t[n * 64 + ((lb ^ (n & 7)) << 3)];
            }
        }
#pragma unroll
        for (int kh = 0; kh < 2; ++kh)
#pragma unroll
            for (int rt = 0; rt < 2; ++rt)
#pragma unroll
                for (int ct = 0; ct < 4; ++ct)
                    acc2[rt][ct] = __builtin_amdgcn_mfma_f32_16x16x32_bf16(
                        ah[rt][kh], bw[ct][kh], acc2[rt][ct], 0, 0, 0);

        // ====== Phase C: W = gelu(w_pre + b2); out = sum_k x[idx[k]] * W[k] ======
        const int bb = gq >> 12;                       // / N_
        const int* ig = eidx + gq * K_;
        const float* xb = x + (size_t)bb * (N_ * C_);
        float s[4] = {0.f, 0.f, 0.f, 0.f};
#pragma unroll
        for (int rt = 0; rt < 2; ++rt)
#pragma unroll
            for (int reg = 0; reg < 4; ++reg) {
                int r = rt * 16 + q * 4 + reg;
                if (r < K_) {
                    int idx = ig[r];
                    const float* xr = xb + idx * C_;
#pragma unroll
                    for (int ct = 0; ct < 4; ++ct) {
                        float wv = gelu_exact(acc2[rt][ct][reg] + b2v[ct]);
                        s[ct] = fmaf(wv, xr[ct * 16 + m16], s[ct]);
                    }
                }
            }
        // reduce across lane-quads (rows live in l>>4 dimension)
#pragma unroll
        for (int ct = 0; ct < 4; ++ct) {
            s[ct] += __shfl_xor(s[ct], 16, 64);
            s[ct] += __shfl_xor(s[ct], 32, 64);
        }
        // lane l writes column l of this group's output row
        float vout = (q == 0) ? s[0] : (q == 1) ? s[1] : (q == 2) ? s[2] : s[3];
        out[(size_t)gq * C_ + l] = vout;
    }
}

extern "C" void kernel_launch(void* const* d_in, const int* in_sizes, int n_in,
                              void* d_out, int out_size, void* d_ws, size_t ws_size,
                              hipStream_t stream) {
    const float* x   = (const float*)d_in[0];
    const float* ef  = (const float*)d_in[1];
    const int*   idx = (const int*)d_in[2];
    const float* W1  = (const float*)d_in[3];
    const float* b1  = (const float*)d_in[4];
    const float* W2  = (const float*)d_in[5];
    const float* b2  = (const float*)d_in[6];
    float* out = (float*)d_out;

    const int nquads = (B_ * N_) / 4;   // 4096
    dim3 grid(512), block(256);
    hipLaunchKernelGGL(cfconv_kernel, grid, block, 0, stream,
                       x, ef, idx, W1, b1, W2, b2, out, nquads);
}